// Round 4
// baseline (1069.993 us; speedup 1.0000x reference)
//
#include <hip/hip_runtime.h>
#include <hip/hip_bf16.h>
#include <float.h>
#include <math.h>

// MultiScaleReadout — single-pass fused, DMA double-buffered version.
// N=500000 nodes, D=256, G=1024 segments (batch sorted), H=L=128.
//   k_prep   : bf16-transpose w1/lp_w -> [128 cols][256 k]
//   k_bounds : boundary-detect sorted batch -> segstart[G+1]
//   k_fused  : SPLIT(4) blocks/segment, 16-row chunks, TWO LDS buffers.
//              Chunk k+1 is prefetched with global_load_lds (async, no VGPRs)
//              while chunk k runs MFMA + gate + online-softmax + pools.
//              Raw s_barrier + manual vmcnt/lgkmcnt so the prefetch is NOT
//              drained at barriers (__syncthreads would vmcnt(0)).
//              LDS is unpadded (DMA requires it); bank spread comes from a
//              16B-chunk XOR swizzle applied on the per-lane GLOBAL source
//              address (c ^= row&7) and on every LDS read.
//   k_merge  : combine 4 partials/segment (softmax-rescaled) -> out.
// Register discipline (r1-r3): live-through ~55 + transients ~25 (unroll 1)
// => fits the 84-VGPR allocation class without scratch.

typedef __bf16 bf16;
typedef __bf16 bf16x8 __attribute__((ext_vector_type(8)));
typedef float f32x4 __attribute__((ext_vector_type(4)));

#define D 256
#define HDIM 128
#define LDIM 128
#define ROWS 16
#define SPLIT 4

// Branchless erf, Abramowitz-Stegun 7.1.26, |err| <= 1.5e-7 (<< bf16 path error).
__device__ __forceinline__ float gelu_f(float v) {
    const float z  = v * 0.70710678118654752f;
    const float az = fabsf(z);
    const float t  = __builtin_amdgcn_rcpf(1.0f + 0.3275911f * az);
    float p = 1.061405429f;
    p = p * t - 1.453152027f;
    p = p * t + 1.421413741f;
    p = p * t - 0.284496736f;
    p = p * t + 0.254829592f;
    p = p * t;
    const float e    = __expf(-z * z);
    const float erfa = 1.0f - p * e;
    const float erfs = copysignf(erfa, z);
    return 0.5f * v * (1.0f + erfs);
}

__device__ __forceinline__ void dma_row16(const float* src, const float* lds_dst) {
    __builtin_amdgcn_global_load_lds(
        (const __attribute__((address_space(1))) void*)src,
        (__attribute__((address_space(3))) void*)lds_dst, 16, 0, 0);
}

// ---------------- Kernel 0: prep (weight transpose to bf16) ----------------
__global__ __launch_bounds__(256) void k_prep(const float* __restrict__ w1,
                                              const float* __restrict__ lpw,
                                              bf16* __restrict__ w1T,
                                              bf16* __restrict__ lpT) {
    int t = blockIdx.x * 256 + threadIdx.x;
    if (t < HDIM * D) {
        int n = t >> 8;   // output col
        int k = t & 255;  // k index
        w1T[t] = (bf16)w1[k * HDIM + n];
        lpT[t] = (bf16)lpw[k * LDIM + n];
    }
}

// ---------------- Kernel 1: segment boundaries from sorted batch ----------------
__global__ __launch_bounds__(256) void k_bounds(const int* __restrict__ batch,
                                                int* __restrict__ segstart,
                                                int N, int G) {
    int i = blockIdx.x * 256 + threadIdx.x;
    if (i >= N) return;
    int b = batch[i];
    if (i == 0) {
        for (int g = 0; g <= b; ++g) segstart[g] = 0;
    } else {
        int p = batch[i - 1];
        for (int g = p + 1; g <= b; ++g) segstart[g] = i;
    }
    if (i == N - 1) {
        for (int g = b + 1; g <= G; ++g) segstart[g] = N;
    }
}

// ---------------- Kernel 2: fused single-pass readout (per segment-part) ----------------
// 256 threads (4 waves). wave w owns output cols [32w,32w+32) of BOTH h and l.
// Pool columns per thread: [4*lane,4*lane+4); its rows: it*4+wave (it=0..3).
__global__ __launch_bounds__(256, 3)
void k_fused(const float* __restrict__ x, const int* __restrict__ segstart,
             const bf16* __restrict__ w1T, const float* __restrict__ b1,
             const float* __restrict__ w2, const float* __restrict__ b2,
             const bf16* __restrict__ lpT, const float* __restrict__ lpb,
             float* __restrict__ psum, float* __restrict__ pmax,
             float* __restrict__ patt, float* __restrict__ pls,
             float* __restrict__ pscal)
{
    __shared__ float xbuf[2][ROWS][D];   // 32 KB, unpadded (DMA dest), XOR-swizzled
    __shared__ float gpart[4][16];       // per-wave gate partials per row

    const int blk  = blockIdx.x;
    const int g    = blk >> 2;
    const int part = blk & 3;
    const int tid  = threadIdx.x;
    const int wave = tid >> 6;
    const int lane = tid & 63;
    const int quad = lane >> 4;
    const int l16  = lane & 15;
    const int s7   = l16 & 7;

    const int gs = segstart[g], ge = segstart[g + 1];
    const int cnt = ge - gs;
    const int per = (cnt + SPLIT - 1) >> 2;
    const int start = gs + part * per;
    const int end   = min(start + per, ge);
    const int nchunk = (end > start) ? ((end - start + ROWS - 1) / ROWS) : 0;

    const int c0 = wave * 32 + l16;
    const int c1 = c0 + 16;
    const float b1c0 = b1[c0], b1c1 = b1[c1];
    const float w2c0 = w2[c0], w2c1 = w2[c1];
    const float lb0  = lpb[c0], lb1 = lpb[c1];
    const float b2c  = b2[0];
    const bf16* wb0 = w1T + c0 * D;
    const bf16* wb1 = w1T + c1 * D;
    const bf16* pb0 = lpT + c0 * D;
    const bf16* pb1 = lpT + c1 * D;

    f32x4 msum = {0.f, 0.f, 0.f, 0.f};
    f32x4 asum = {0.f, 0.f, 0.f, 0.f};
    f32x4 mmax = {-FLT_MAX, -FLT_MAX, -FLT_MAX, -FLT_MAX};
    float ls0 = 0.f, ls1 = 0.f;
    float m_run = -FLT_MAX, denom = 0.f;   // replicated in all threads

    // prologue: stage chunk 0 into buffer 0 (async, no VGPRs)
    if (nchunk > 0) {
        const int vr0 = min(ROWS, end - start);
        #pragma unroll
        for (int it = 0; it < 4; ++it) {
            const int row = it * 4 + wave;           // wave-uniform
            if (row < vr0)
                dma_row16(x + (long)(start + row) * D + ((lane ^ (row & 7)) << 2),
                          &xbuf[0][row][0]);
        }
    }

    int cur = 0;
    for (int ck = 0; ck < nchunk; ++ck) {
        const int base = start + ck * ROWS;
        const int vr   = min(ROWS, end - base);

        // ---- barrier A: my DMA done; all waves finished previous chunk ----
        asm volatile("s_waitcnt vmcnt(0)" ::: "memory");
        __builtin_amdgcn_s_barrier();
        __builtin_amdgcn_sched_barrier(0);

        float (*xb)[D] = xbuf[cur];

        // ---- MFMA: h = x@w1, l = x@lp_w (bf16 frags cvt'd from f32 LDS) ----
        const f32x4 zf = {0.f, 0.f, 0.f, 0.f};
        f32x4 h0 = zf, h1 = zf, l0 = zf, l1 = zf;
        #pragma unroll 1   // keep transient B-frag pressure to one kt at a time
        for (int kt = 0; kt < 8; ++kt) {
            const int k0 = kt * 32 + quad * 8;
            const bf16x8 bw0v = *(const bf16x8*)(wb0 + k0);
            const bf16x8 bw1v = *(const bf16x8*)(wb1 + k0);
            const bf16x8 bp0v = *(const bf16x8*)(pb0 + k0);
            const bf16x8 bp1v = *(const bf16x8*)(pb1 + k0);
            const int cch = kt * 8 + quad * 2;       // logical 16B-chunk (even)
            const int p0  = cch ^ s7;
            const int p1  = p0 ^ 1;
            const float* xp = &xb[l16][0];
            const f32x4 fa = *(const f32x4*)(xp + p0 * 4);
            const f32x4 fb = *(const f32x4*)(xp + p1 * 4);
            bf16x8 a;
            a[0]=(bf16)fa[0]; a[1]=(bf16)fa[1]; a[2]=(bf16)fa[2]; a[3]=(bf16)fa[3];
            a[4]=(bf16)fb[0]; a[5]=(bf16)fb[1]; a[6]=(bf16)fb[2]; a[7]=(bf16)fb[3];
            h0 = __builtin_amdgcn_mfma_f32_16x16x32_bf16(a, bw0v, h0, 0, 0, 0);
            h1 = __builtin_amdgcn_mfma_f32_16x16x32_bf16(a, bw1v, h1, 0, 0, 0);
            l0 = __builtin_amdgcn_mfma_f32_16x16x32_bf16(a, bp0v, l0, 0, 0, 0);
            l1 = __builtin_amdgcn_mfma_f32_16x16x32_bf16(a, bp1v, l1, 0, 0, 0);
        }

        // ---- prefetch chunk ck+1 (after kloop so its vmcnt waits don't drain it;
        //      latency covered by gate/softmax/pool phases ~2000 cy) ----
        if (ck + 1 < nchunk) {
            const int nb  = base + ROWS;
            const int vrn = min(ROWS, end - nb);
            #pragma unroll
            for (int it = 0; it < 4; ++it) {
                const int row = it * 4 + wave;
                if (row < vrn)
                    dma_row16(x + (long)(nb + row) * D + ((lane ^ (row & 7)) << 2),
                              &xbuf[cur ^ 1][row][0]);
            }
        }

        // ---- gate row partials: gelu(h+b1)*w2, reduce over wave's 32 cols ----
        #pragma unroll
        for (int r = 0; r < 4; ++r) {
            float v = gelu_f(h0[r] + b1c0) * w2c0
                    + gelu_f(h1[r] + b1c1) * w2c1;
            v += __shfl_down(v, 8, 16);
            v += __shfl_down(v, 4, 16);
            v += __shfl_down(v, 2, 16);
            v += __shfl_down(v, 1, 16);
            if (l16 == 0) gpart[wave][quad * 4 + r] = v;
        }

        // ---- barrier B: gpart visible (lgkm only — DO NOT drain vmcnt) ----
        asm volatile("s_waitcnt lgkmcnt(0)" ::: "memory");
        __builtin_amdgcn_s_barrier();
        __builtin_amdgcn_sched_barrier(0);

        // ---- online softmax chunk stats (redundant in every wave) ----
        float gv = -FLT_MAX;
        if (lane < vr)
            gv = gpart[0][lane] + gpart[1][lane] + gpart[2][lane] + gpart[3][lane] + b2c;
        float cm = gv;
        #pragma unroll
        for (int off = 32; off > 0; off >>= 1) cm = fmaxf(cm, __shfl_xor(cm, off));
        const float m_new = fmaxf(m_run, cm);
        const float fr = __expf(m_run - m_new);          // 0 on first chunk
        const float ew = (lane < vr) ? __expf(gv - m_new) : 0.f;
        float se = ew;
        #pragma unroll
        for (int off = 32; off > 0; off >>= 1) se += __shfl_xor(se, off);
        denom = denom * fr + se;
        m_run = m_new;

        // ---- local pool sums (from MFMA accumulators) ----
        #pragma unroll
        for (int r = 0; r < 4; ++r) {
            if (quad * 4 + r < vr) {
                ls0 += gelu_f(l0[r] + lb0);
                ls1 += gelu_f(l1[r] + lb1);
            }
        }

        // ---- mean/max/att from f32 LDS (swizzled read; chunk index = lane) ----
        asum[0] *= fr; asum[1] *= fr; asum[2] *= fr; asum[3] *= fr;
        #pragma unroll
        for (int it = 0; it < 4; ++it) {
            const int row = it * 4 + wave;               // wave-uniform guard
            if (row < vr) {
                const float e = __shfl(ew, row);         // e lives in lane==row
                const f32x4 v = *(const f32x4*)(&xb[row][(lane ^ (row & 7)) << 2]);
                msum[0] += v[0]; msum[1] += v[1]; msum[2] += v[2]; msum[3] += v[3];
                mmax[0] = fmaxf(mmax[0], v[0]); mmax[1] = fmaxf(mmax[1], v[1]);
                mmax[2] = fmaxf(mmax[2], v[2]); mmax[3] = fmaxf(mmax[3], v[3]);
                asum[0] += e * v[0]; asum[1] += e * v[1];
                asum[2] += e * v[2]; asum[3] += e * v[3];
            }
        }
        cur ^= 1;
        // no end-of-iter barrier: barrier A (top of next iter) fences reuse.
    }

    // ---------------- epilogue: per-part partials ----------------
    ls0 += __shfl_xor(ls0, 16); ls0 += __shfl_xor(ls0, 32);
    ls1 += __shfl_xor(ls1, 16); ls1 += __shfl_xor(ls1, 32);

    __syncthreads();                      // all loop LDS reads done
    float* red = &xbuf[0][0][0];          // 3 KB reduce buffer aliases xbuf
    const int cb = (wave << 8) + (lane << 2);
    *(f32x4*)(&red[cb])        = msum;
    *(f32x4*)(&red[1024 + cb]) = asum;
    *(f32x4*)(&red[2048 + cb]) = mmax;
    if (quad == 0) {
        pls[(long)blk * LDIM + c0] = ls0;
        pls[(long)blk * LDIM + c1] = ls1;
    }
    if (tid == 0) {
        const int pcnt = (end > start) ? (end - start) : 0;
        pscal[(long)blk * 4 + 0] = m_run;
        pscal[(long)blk * 4 + 1] = denom;
        pscal[(long)blk * 4 + 2] = (float)pcnt;
    }
    __syncthreads();
    {
        const int col = tid;   // 0..255
        const float s  = red[col]        + red[256 + col]  + red[512 + col]  + red[768 + col];
        const float a  = red[1024 + col] + red[1280 + col] + red[1536 + col] + red[1792 + col];
        const float mx = fmaxf(fmaxf(red[2048 + col], red[2304 + col]),
                               fmaxf(red[2560 + col], red[2816 + col]));
        psum[(long)blk * 256 + col] = s;
        patt[(long)blk * 256 + col] = a;
        pmax[(long)blk * 256 + col] = mx;
    }
}

// ---------------- Kernel 3: merge SPLIT partials per segment ----------------
__global__ __launch_bounds__(256) void k_merge(
    const float* __restrict__ psum, const float* __restrict__ pmax,
    const float* __restrict__ patt, const float* __restrict__ pls,
    const float* __restrict__ pscal, float* __restrict__ out)
{
    const int g   = blockIdx.x;
    const int tid = threadIdx.x;
    __shared__ float sm[SPLIT], sd[SPLIT], sc[SPLIT];
    if (tid < SPLIT) {
        sm[tid] = pscal[(long)(g * SPLIT + tid) * 4 + 0];
        sd[tid] = pscal[(long)(g * SPLIT + tid) * 4 + 1];
        sc[tid] = pscal[(long)(g * SPLIT + tid) * 4 + 2];
    }
    __syncthreads();
    const float M   = fmaxf(fmaxf(sm[0], sm[1]), fmaxf(sm[2], sm[3]));
    const float cnt = sc[0] + sc[1] + sc[2] + sc[3];
    float w[SPLIT];
    float denom = 0.f;
    #pragma unroll
    for (int p = 0; p < SPLIT; ++p) {
        w[p] = expf(sm[p] - M);          // empty part -> 0; all-empty -> 1*0
        denom += sd[p] * w[p];
    }
    const float inv  = 1.0f / fmaxf(cnt, 1.0f);
    const float invd = (denom > 0.f) ? 1.0f / denom : 0.f;
    const long  o    = (long)g * 896;
    const long  pb   = (long)g * SPLIT * 256;
    {
        const int col = tid;
        float s = 0.f, a = 0.f, mx = -FLT_MAX;
        #pragma unroll
        for (int p = 0; p < SPLIT; ++p) {
            s += psum[pb + p * 256 + col];
            mx = fmaxf(mx, pmax[pb + p * 256 + col]);
            a += patt[pb + p * 256 + col] * w[p];
        }
        out[o + col]       = s * inv;
        out[o + 256 + col] = (cnt > 0.f) ? mx : -INFINITY;
        out[o + 512 + col] = a * invd;
    }
    if (tid < 128) {
        const long lb = (long)g * SPLIT * 128;
        float s = 0.f;
        #pragma unroll
        for (int p = 0; p < SPLIT; ++p) s += pls[lb + p * 128 + tid];
        out[o + 768 + tid] = s * inv;
    }
}

// ---------------- launch ----------------
extern "C" void kernel_launch(void* const* d_in, const int* in_sizes, int n_in,
                              void* d_out, int out_size, void* d_ws, size_t ws_size,
                              hipStream_t stream) {
    const float* x   = (const float*)d_in[0];
    const int* batch = (const int*)d_in[1];
    const float* w1  = (const float*)d_in[2];
    const float* b1  = (const float*)d_in[3];
    const float* w2  = (const float*)d_in[4];
    const float* b2  = (const float*)d_in[5];
    const float* lpw = (const float*)d_in[6];
    const float* lpb = (const float*)d_in[7];
    float* out = (float*)d_out;

    const int N = in_sizes[0] / D;
    const int G = out_size / 896;
    const int NB = SPLIT * G;

    char* ws = (char*)d_ws;
    size_t off = 0;
    auto alloc = [&](size_t bytes) { void* p = ws + off; off = (off + bytes + 255) & ~(size_t)255; return p; };
    bf16*  w1T      = (bf16*)alloc((size_t)HDIM * D * sizeof(bf16));
    bf16*  lpT      = (bf16*)alloc((size_t)LDIM * D * sizeof(bf16));
    int*   segstart = (int*)alloc((size_t)(G + 1) * sizeof(int));
    float* psum     = (float*)alloc((size_t)NB * 256 * sizeof(float));
    float* pmax     = (float*)alloc((size_t)NB * 256 * sizeof(float));
    float* patt     = (float*)alloc((size_t)NB * 256 * sizeof(float));
    float* pls      = (float*)alloc((size_t)NB * 128 * sizeof(float));
    float* pscal    = (float*)alloc((size_t)NB * 4 * sizeof(float));

    k_prep<<<(HDIM * D + 255) / 256, 256, 0, stream>>>(w1, lpw, w1T, lpT);
    k_bounds<<<(N + 255) / 256, 256, 0, stream>>>(batch, segstart, N, G);
    k_fused<<<NB, 256, 0, stream>>>(x, segstart, w1T, b1, w2, b2, lpT, lpb,
                                    psum, pmax, patt, pls, pscal);
    k_merge<<<G, 256, 0, stream>>>(psum, pmax, patt, pls, pscal, out);
}